// Round 7
// baseline (302.114 us; speedup 1.0000x reference)
//
#include <hip/hip_runtime.h>
#include <math.h>

// ---------------------------------------------------------------------------
// ISTFTHead on gfx950 — fp16 MFMA path, round 7.
//
// Round-6 post-mortem: barrier-count halving bought 2% — the staged-LDS
// 2-barrier K-loop is the structural limiter (m97 plateau). Since operands
// are pre-swizzled in exact MFMA fragment order, round 7 deletes LDS staging
// entirely: each wave global_load_dwordx4's its fragments straight into
// VGPRs, software-pipelined 2-deep. No __syncthreads in either GEMM; the
// compiler emits fine-grained vmcnt waits (AITER-style). B fragments are
// re-read per wave from L2 (~0.9 GB aggregate, overlapped with MFMA).
// Epilogues / conv kernels / ola byte-identical to round 6.
//
// Fragment order for mfma_f32_16x16x32_f16 (verified rounds 2-6):
//   A tile: elem(lane,j) = A[m = lane&15][k = (lane>>4)*8 + j]
//   B tile: elem(lane,j) = B[k = (lane>>4)*8 + j][n = lane&15]
//   C/D:    row = (lane>>4)*4 + r, col = lane&15
//   A lane fragment = 16 B at tile_base + lane*16.
//
// Workspace map (bytes):
//   A2  [0,          35651584)   16384 x 1088 f16, [mb128][kt34][mts8][l][j]
//                                kt 0..16 = Sr rows, 17..33 = Si rows
//   B2  [35651584,   36904960)   mirror basis, [nblk6][kt34][nt6][l][j]
//   A1  [37879808,   71434240)   [xh|xl],      [mblk128][kt32][mts8][l][j]
//   B1  [71434240,   72613888)   Wh,           [bx9][kt16][t8][l][j]
//   frames [37879808, 71434240)  16384 x 1024 f16 (aliases A1 — dead by GEMM2)
// ---------------------------------------------------------------------------

using half8 = __attribute__((ext_vector_type(8))) _Float16;
using f32x4 = __attribute__((ext_vector_type(4))) float;

#define TWO_PI_OVER_1024 0.006135923151542565f

#define OFF_A2 0
#define OFF_B2 35651584UL
#define OFF_A1 37879808UL
#define OFF_B1 71434240UL
#define OFF_FR 37879808UL

__device__ __forceinline__ float hannf(int s) {
    return 0.5f * (1.0f - cosf(TWO_PI_OVER_1024 * (float)s));
}

// ---------------- conversion kernels ----------------

// x (16384x512 f32) -> A1 fragment-swizzled fp16 [xh (kt 0..15) | xl (kt 16..31)]
__global__ __launch_bounds__(256)
void conv_x_k(const float* __restrict__ x, _Float16* __restrict__ A1)
{
    const size_t tid = (size_t)blockIdx.x * 256 + threadIdx.x;   // 2,097,152
    const int l   = (int)(tid & 63);
    const size_t f = tid >> 6;
    const int mts = (int)(f & 7);
    const size_t g = f >> 3;
    const int kt  = (int)(g & 31);
    const int mtb = (int)(g >> 5);
    const int m   = mtb * 128 + mts * 16 + (l & 15);
    const int k0  = (kt & 15) * 32 + (l >> 4) * 8;
    const bool hi = (kt < 16);
    const float* xp = x + (size_t)m * 512 + k0;
    const float4 v0 = *(const float4*)xp;
    const float4 v1 = *(const float4*)(xp + 4);
    const float vv[8] = {v0.x, v0.y, v0.z, v0.w, v1.x, v1.y, v1.z, v1.w};
    half8 o;
#pragma unroll
    for (int j = 0; j < 8; ++j) {
        _Float16 h = (_Float16)vv[j];
        o[j] = hi ? h : (_Float16)(vv[j] - (float)h);
    }
    *(half8*)(A1 + tid * 8) = o;
}

// W (512x1026 f32) -> B1 (Wh only) fragment-swizzled fp16, per bx(0..8):
// tiles 0..3 = mag cols (bx*64..+63), tiles 4..7 = phase cols (513 + same).
__global__ __launch_bounds__(256)
void conv_w_k(const float* __restrict__ W, _Float16* __restrict__ B1)
{
    const int tid = blockIdx.x * 256 + threadIdx.x;              // 73,728
    const int l  = tid & 63;
    const int f  = tid >> 6;
    const int t8 = f & 7;
    const int g  = f >> 3;
    const int kt = g & 15;
    const int bx = g >> 4;
    const int side = t8 >> 2;
    const int nt   = t8 & 3;
    const int c    = bx * 64 + nt * 16 + (l & 15);               // [0,576)
    const int k0   = kt * 32 + (l >> 4) * 8;
    const int wcol = side ? (513 + c) : c;
    half8 o;
#pragma unroll
    for (int j = 0; j < 8; ++j) {
        float v = (c < 513) ? W[(size_t)(k0 + j) * 1026 + wcol] : 0.0f;
        o[j] = (_Float16)v;
    }
    *(half8*)(B1 + (size_t)tid * 8) = o;
}

// Mirror-symmetric windowed irfft basis, n in [0,576), fragment order
// [nblk6][kt34][nt6][l][j]. kk = kt*32 + (l>>4)*8 + j:
//   kk < 544 : cos row for bin kk   (pairs with Sr)
//   kk >= 544: -sin row for bin kk-544 (pairs with Si)
// 78,336 threads = 306 blocks (threads = half8 count, NOT half count).
__global__ __launch_bounds__(256)
void basis_k(_Float16* __restrict__ B2)
{
    const int tid = blockIdx.x * 256 + threadIdx.x;              // 78,336
    const int l  = tid & 63;
    const int f  = tid >> 6;
    const int nt = f % 6;
    const int g  = f / 6;
    const int kt = g % 34;
    const int nblk = g / 34;
    const int n  = nblk * 96 + nt * 16 + (l & 15);
    const int kk0 = kt * 32 + (l >> 4) * 8;
    const float win = hannf(n) * (1.0f / 1024.0f);
    half8 o;
#pragma unroll
    for (int j = 0; j < 8; ++j) {
        const int kk = kk0 + j;
        float v = 0.0f;
        if (kk < 544) {
            const int k = kk;
            if (k < 513) {
                const float coef = (k == 0 || k == 512) ? 1.0f : 2.0f;
                v = coef * cosf(TWO_PI_OVER_1024 * (float)((k * n) & 1023)) * win;
            }
        } else {
            const int k = kk - 544;
            if (k < 513) {
                const float coef = (k == 0 || k == 512) ? 1.0f : 2.0f;
                v = -coef * sinf(TWO_PI_OVER_1024 * (float)((k * n) & 1023)) * win;
            }
        }
        o[j] = (_Float16)v;
    }
    *(half8*)(B2 + (size_t)tid * 8) = o;
}

// ---------------- GEMM1: x@W + b, fused activation, swizzled A2 output ------
// Direct-fragment GEMM: no LDS, no barriers. Wave w owns m-tiles {2w,2w+1},
// all 8 n-tiles. 16 k-tiles, 2-deep software pipeline: 12 dwordx4 loads +
// 24 MFMA per kt.

__device__ __forceinline__ void store_a2(_Float16* __restrict__ A2, int m, int k, float v)
{
    const int mt2 = m >> 4, mr = m & 15;
    const int kt2 = k >> 5, kc = k & 31;
    const int l2 = (kc >> 3) * 16 + mr;
    const int j2 = kc & 7;
    const int mtb = mt2 >> 3, mts = mt2 & 7;
    const size_t idx = ((((size_t)mtb * 34 + kt2) * 8 + mts) * 64 + l2) * 8 + j2;
    A2[idx] = (_Float16)v;
}

__global__ __launch_bounds__(256)
void gemm1_k(const _Float16* __restrict__ A, const _Float16* __restrict__ B,
             const float* __restrict__ bias, _Float16* __restrict__ A2)
{
    const int t = threadIdx.x, w = t >> 6, l = t & 63;

    // XCD-aware swizzle: 1152 blocks, 144 per XCD = 16 mblk x 9 bx.
    const int lin = blockIdx.x;
    const int xcd = lin & 7, slot = lin >> 3;
    const int mblk = xcd * 16 + slot / 9;
    const int bx   = slot % 9;

    f32x4 acc[2][8];
#pragma unroll
    for (int i = 0; i < 2; ++i)
#pragma unroll
        for (int j = 0; j < 8; ++j) acc[i][j] = (f32x4)0.0f;

    const int lane8 = l * 8;
    const int w2 = 2 * w;
    // tile (kt, mts) at ((mblk*32 + kt)*8 + mts)*512 halfs; lane frag +l*8
    const _Float16* Abase = A + (size_t)mblk * 32 * 8 * 512 + lane8;
    const _Float16* Bbase = B + (size_t)bx * 16 * 8 * 512 + lane8;

    half8 ah[2][2], al[2][2], bh[2][8];

#define G1_LOAD(kt, s)                                                          \
    {                                                                           \
        _Pragma("unroll")                                                       \
        for (int i = 0; i < 2; ++i) {                                           \
            ah[s][i] = *(const half8*)(Abase + ((size_t)(kt) * 8 + w2 + i) * 512);       \
            al[s][i] = *(const half8*)(Abase + ((size_t)(16 + (kt)) * 8 + w2 + i) * 512);\
        }                                                                       \
        _Pragma("unroll")                                                       \
        for (int j = 0; j < 8; ++j)                                             \
            bh[s][j] = *(const half8*)(Bbase + ((size_t)(kt) * 8 + j) * 512);   \
    }

    G1_LOAD(0, 0)
#pragma unroll
    for (int kt = 0; kt < 16; ++kt) {
        const int s = kt & 1;
        if (kt + 1 < 16) G1_LOAD(kt + 1, s ^ 1)
#pragma unroll
        for (int j = 0; j < 8; ++j) {
            acc[0][j] = __builtin_amdgcn_mfma_f32_16x16x32_f16(ah[s][0], bh[s][j], acc[0][j], 0, 0, 0);
            acc[1][j] = __builtin_amdgcn_mfma_f32_16x16x32_f16(ah[s][1], bh[s][j], acc[1][j], 0, 0, 0);
            acc[0][j] = __builtin_amdgcn_mfma_f32_16x16x32_f16(al[s][0], bh[s][j], acc[0][j], 0, 0, 0);
            acc[1][j] = __builtin_amdgcn_mfma_f32_16x16x32_f16(al[s][1], bh[s][j], acc[1][j], 0, 0, 0);
        }
    }
#undef G1_LOAD

    // epilogue: activation + swizzled fp16 stores (identical to round 6)
    const int r4 = (l >> 4) * 4, c16 = l & 15;
#pragma unroll
    for (int mt = 0; mt < 2; ++mt) {
        const int mbase = mblk * 128 + (w2 + mt) * 16 + r4;
#pragma unroll
        for (int nt = 0; nt < 4; ++nt) {
            const int c = bx * 64 + nt * 16 + c16;
            const bool valid = (c < 513);
            const float bm = valid ? bias[c] : 0.0f;
            const float bp = valid ? bias[513 + c] : 0.0f;
#pragma unroll
            for (int r = 0; r < 4; ++r) {
                float Sr = 0.0f, Si = 0.0f;
                if (valid) {
                    const float mag = fminf(expf(acc[mt][nt][r] + bm), 100.0f);
                    const float ph  = acc[mt][nt + 4][r] + bp;
                    Sr = mag * cosf(ph);
                    Si = mag * sinf(ph);
                }
                if (c < 544) {
                    store_a2(A2, mbase + r, c, Sr);
                    store_a2(A2, mbase + r, 544 + c, Si);
                }
            }
        }
    }
}

// ---------------- GEMM2: mirror-symmetric frames = A2 @ basis ---------------
// Direct-fragment GEMM, no LDS/barriers. Block 128m x 96n; wave w owns
// 4 m-tiles (wm) x 3 n-tiles (wn). 34 k-tiles: kt<17 -> accC (cos/Sr),
// kt>=17 -> accD (sin/Si). 7 loads + 12 MFMA per kt, 2-deep pipeline.

__global__ __launch_bounds__(256)
void gemm2_k(const _Float16* __restrict__ A, const _Float16* __restrict__ Bas,
             _Float16* __restrict__ C)
{
    const int t = threadIdx.x, w = t >> 6, l = t & 63;

    // XCD-aware swizzle: 768 blocks, 96 per XCD = 16 mblk x 6 nblk.
    const int lin = blockIdx.x;
    const int xcd = lin & 7, slot = lin >> 3;
    const int mblk = xcd * 16 + slot / 6;   // [0,128) — 128-row chunk
    const int nblk = slot % 6;              // [0,6)   — 96-col chunk

    const int wm = (w & 1) * 4, wn = (w >> 1) * 3;

    f32x4 accC[4][3], accD[4][3];
#pragma unroll
    for (int i = 0; i < 4; ++i)
#pragma unroll
        for (int j = 0; j < 3; ++j) { accC[i][j] = (f32x4)0.0f; accD[i][j] = (f32x4)0.0f; }

    const int lane8 = l * 8;
    // A tile (kt, mts) at ((mblk*34 + kt)*8 + mts)*512; B tile (kt, nt) at
    // ((nblk*34 + kt)*6 + nt)*512.
    const _Float16* Abase = A + (size_t)mblk * 34 * 8 * 512 + lane8;
    const _Float16* Bbase = Bas + (size_t)nblk * 34 * 6 * 512 + lane8;

    half8 a[2][4], b[2][3];

#define G2_LOAD(kt, s)                                                          \
    {                                                                           \
        _Pragma("unroll")                                                       \
        for (int i = 0; i < 4; ++i)                                             \
            a[s][i] = *(const half8*)(Abase + ((size_t)(kt) * 8 + wm + i) * 512);\
        _Pragma("unroll")                                                       \
        for (int j = 0; j < 3; ++j)                                             \
            b[s][j] = *(const half8*)(Bbase + ((size_t)(kt) * 6 + wn + j) * 512);\
    }

    G2_LOAD(0, 0)
#pragma unroll
    for (int kt = 0; kt < 34; ++kt) {
        const int s = kt & 1;
        if (kt + 1 < 34) G2_LOAD(kt + 1, s ^ 1)
        if (kt < 17) {
#pragma unroll
            for (int i = 0; i < 4; ++i)
#pragma unroll
                for (int j = 0; j < 3; ++j)
                    accC[i][j] = __builtin_amdgcn_mfma_f32_16x16x32_f16(a[s][i], b[s][j], accC[i][j], 0, 0, 0);
        } else {
#pragma unroll
            for (int i = 0; i < 4; ++i)
#pragma unroll
                for (int j = 0; j < 3; ++j)
                    accD[i][j] = __builtin_amdgcn_mfma_f32_16x16x32_f16(a[s][i], b[s][j], accD[i][j], 0, 0, 0);
        }
    }
#undef G2_LOAD

    // epilogue: frames[n] = C+D, frames[1024-n] = C-D (identical to round 6)
    const int r4 = (l >> 4) * 4, c0 = l & 15;
#pragma unroll
    for (int i = 0; i < 4; ++i) {
        const int m = mblk * 128 + (wm + i) * 16 + r4;
#pragma unroll
        for (int j = 0; j < 3; ++j) {
            const int n = nblk * 96 + (wn + j) * 16 + c0;
#pragma unroll
            for (int r = 0; r < 4; ++r) {
                const float cv = accC[i][j][r];
                const float dv = accD[i][j][r];
                _Float16* row = C + (size_t)(m + r) * 1024;
                if (n < 513)           row[n]        = (_Float16)(cv + dv);
                if (n >= 1 && n < 512) row[1024 - n] = (_Float16)(cv - dv);
            }
        }
    }
}

// ---------------- overlap-add + envelope ------------------------------------

__global__ __launch_bounds__(256)
void ola_kernel(const _Float16* __restrict__ frames, float* __restrict__ out)
{
    const int idx = blockIdx.x * 256 + threadIdx.x;   // over 8 * 524288
    const int b = idx >> 19;
    const int j = idx & 524287;
    const int n = j + 384;

    int t_hi = n >> 8;
    if (t_hi > 2047) t_hi = 2047;
    const int t_lo = (n >= 1023) ? ((n - 1023 + 255) >> 8) : 0;

    float acc = 0.0f, env = 0.0f;
    for (int tt = t_lo; tt <= t_hi; ++tt) {
        const int s = n - (tt << 8);
        const float wv = hannf(s);
        acc += (float)frames[(((size_t)(b * 2048 + tt)) << 10) + s];
        env += wv * wv;
    }
    out[idx] = acc / env;
}

// ---------------- launch ----------------------------------------------------

extern "C" void kernel_launch(void* const* d_in, const int* in_sizes, int n_in,
                              void* d_out, int out_size, void* d_ws, size_t ws_size,
                              hipStream_t stream)
{
    const float* x = (const float*)d_in[0];   // 16384 x 512
    const float* W = (const float*)d_in[1];   // 512 x 1026
    const float* b = (const float*)d_in[2];   // 1026
    float* out = (float*)d_out;               // 8 x 524288
    char* ws = (char*)d_ws;

    _Float16* A2 = (_Float16*)(ws + OFF_A2);
    _Float16* B2 = (_Float16*)(ws + OFF_B2);
    _Float16* A1 = (_Float16*)(ws + OFF_A1);
    _Float16* B1 = (_Float16*)(ws + OFF_B1);
    _Float16* frames = (_Float16*)(ws + OFF_FR);

    conv_x_k<<<8192, 256, 0, stream>>>(x, A1);
    conv_w_k<<<288, 256, 0, stream>>>(W, B1);
    basis_k<<<306, 256, 0, stream>>>(B2);

    gemm1_k<<<1152, 256, 0, stream>>>(A1, B1, b, A2);
    gemm2_k<<<768, 256, 0, stream>>>(A2, B2, frames);

    ola_kernel<<<out_size / 256, 256, 0, stream>>>(frames, out);
}

// Round 8
// 231.916 us; speedup vs baseline: 1.3027x; 1.3027x over previous
//
#include <hip/hip_runtime.h>
#include <math.h>

// ---------------------------------------------------------------------------
// ISTFTHead on gfx950 — fp16 MFMA path, round 8.
//
// Round-7 post-mortem: pure direct-fragment GEMM was L2-BW bound (B re-read
// per wave: ~3.6 GB -> 170 us, MfmaUtil 8%). Round-6 LDS version was
// barrier-drain bound (16 drains). Round 8 hybrid:
//   - B (shared by all 4 waves) staged into LDS in COARSE phases
//     (gemm1: 2 phases x 64 KB; gemm2: 4 phases x <=54 KB).
//   - A (wave-exclusive) loaded global->VGPR directly, 2-deep pipeline,
//     no barriers inside a phase; compiler emits fine-grained vmcnt/lgkmcnt.
//   - gemm1: 3 barriers total (was 16); gemm2: 8 (was 34).
//   - gemm2 waves remapped: wave w owns m-tiles {2w,2w+1} x all 6 n-tiles
//     so A loads are exclusive (no cross-wave duplication).
//
// Fragment order for mfma_f32_16x16x32_f16 (verified rounds 2-6):
//   A tile: elem(lane,j) = A[m = lane&15][k = (lane>>4)*8 + j]
//   B tile: elem(lane,j) = B[k = (lane>>4)*8 + j][n = lane&15]
//   C/D:    row = (lane>>4)*4 + r, col = lane&15
//   lane fragment = 16 B at tile_base + lane*16.
//
// Workspace map (bytes):
//   A2  [0,          35651584)   16384 x 1088 f16, [mb128][kt34][mts8][l][j]
//                                kt 0..16 = Sr rows, 17..33 = Si rows
//   B2  [35651584,   36904960)   mirror basis, [nblk6][kt34][nt6][l][j]
//   A1  [37879808,   71434240)   [xh|xl],      [mblk128][kt32][mts8][l][j]
//   B1  [71434240,   72613888)   Wh,           [bx9][kt16][t8][l][j]
//   frames [37879808, 71434240)  16384 x 1024 f16 (aliases A1 — dead by GEMM2)
// ---------------------------------------------------------------------------

using half8 = __attribute__((ext_vector_type(8))) _Float16;
using f32x4 = __attribute__((ext_vector_type(4))) float;

#define TWO_PI_OVER_1024 0.006135923151542565f

#define OFF_A2 0
#define OFF_B2 35651584UL
#define OFF_A1 37879808UL
#define OFF_B1 71434240UL
#define OFF_FR 37879808UL

__device__ __forceinline__ float hannf(int s) {
    return 0.5f * (1.0f - cosf(TWO_PI_OVER_1024 * (float)s));
}

// async global->LDS, 16B per lane. Global addr per-lane; LDS dest wave-uniform.
__device__ __forceinline__ void stage16(const void* g, void* lds) {
    __builtin_amdgcn_global_load_lds(
        (const __attribute__((address_space(1))) void*)g,
        (__attribute__((address_space(3))) void*)lds,
        16, 0, 0);
}

// ---------------- conversion kernels ----------------

// x (16384x512 f32) -> A1 fragment-swizzled fp16 [xh (kt 0..15) | xl (kt 16..31)]
__global__ __launch_bounds__(256)
void conv_x_k(const float* __restrict__ x, _Float16* __restrict__ A1)
{
    const size_t tid = (size_t)blockIdx.x * 256 + threadIdx.x;   // 2,097,152
    const int l   = (int)(tid & 63);
    const size_t f = tid >> 6;
    const int mts = (int)(f & 7);
    const size_t g = f >> 3;
    const int kt  = (int)(g & 31);
    const int mtb = (int)(g >> 5);
    const int m   = mtb * 128 + mts * 16 + (l & 15);
    const int k0  = (kt & 15) * 32 + (l >> 4) * 8;
    const bool hi = (kt < 16);
    const float* xp = x + (size_t)m * 512 + k0;
    const float4 v0 = *(const float4*)xp;
    const float4 v1 = *(const float4*)(xp + 4);
    const float vv[8] = {v0.x, v0.y, v0.z, v0.w, v1.x, v1.y, v1.z, v1.w};
    half8 o;
#pragma unroll
    for (int j = 0; j < 8; ++j) {
        _Float16 h = (_Float16)vv[j];
        o[j] = hi ? h : (_Float16)(vv[j] - (float)h);
    }
    *(half8*)(A1 + tid * 8) = o;
}

// W (512x1026 f32) -> B1 (Wh only) fragment-swizzled fp16, per bx(0..8):
// tiles 0..3 = mag cols (bx*64..+63), tiles 4..7 = phase cols (513 + same).
__global__ __launch_bounds__(256)
void conv_w_k(const float* __restrict__ W, _Float16* __restrict__ B1)
{
    const int tid = blockIdx.x * 256 + threadIdx.x;              // 73,728
    const int l  = tid & 63;
    const int f  = tid >> 6;
    const int t8 = f & 7;
    const int g  = f >> 3;
    const int kt = g & 15;
    const int bx = g >> 4;
    const int side = t8 >> 2;
    const int nt   = t8 & 3;
    const int c    = bx * 64 + nt * 16 + (l & 15);               // [0,576)
    const int k0   = kt * 32 + (l >> 4) * 8;
    const int wcol = side ? (513 + c) : c;
    half8 o;
#pragma unroll
    for (int j = 0; j < 8; ++j) {
        float v = (c < 513) ? W[(size_t)(k0 + j) * 1026 + wcol] : 0.0f;
        o[j] = (_Float16)v;
    }
    *(half8*)(B1 + (size_t)tid * 8) = o;
}

// Mirror-symmetric windowed irfft basis, n in [0,576), fragment order
// [nblk6][kt34][nt6][l][j]. kk = kt*32 + (l>>4)*8 + j:
//   kk < 544 : cos row for bin kk   (pairs with Sr)
//   kk >= 544: -sin row for bin kk-544 (pairs with Si)
// 78,336 threads = 306 blocks (threads = half8 count, NOT half count).
__global__ __launch_bounds__(256)
void basis_k(_Float16* __restrict__ B2)
{
    const int tid = blockIdx.x * 256 + threadIdx.x;              // 78,336
    const int l  = tid & 63;
    const int f  = tid >> 6;
    const int nt = f % 6;
    const int g  = f / 6;
    const int kt = g % 34;
    const int nblk = g / 34;
    const int n  = nblk * 96 + nt * 16 + (l & 15);
    const int kk0 = kt * 32 + (l >> 4) * 8;
    const float win = hannf(n) * (1.0f / 1024.0f);
    half8 o;
#pragma unroll
    for (int j = 0; j < 8; ++j) {
        const int kk = kk0 + j;
        float v = 0.0f;
        if (kk < 544) {
            const int k = kk;
            if (k < 513) {
                const float coef = (k == 0 || k == 512) ? 1.0f : 2.0f;
                v = coef * cosf(TWO_PI_OVER_1024 * (float)((k * n) & 1023)) * win;
            }
        } else {
            const int k = kk - 544;
            if (k < 513) {
                const float coef = (k == 0 || k == 512) ? 1.0f : 2.0f;
                v = -coef * sinf(TWO_PI_OVER_1024 * (float)((k * n) & 1023)) * win;
            }
        }
        o[j] = (_Float16)v;
    }
    *(half8*)(B2 + (size_t)tid * 8) = o;
}

// ---------------- GEMM1: x@W + b, fused activation, swizzled A2 output ------
// Hybrid: B staged in 2 phases of 64 KB (8 kt x 8 tiles); A direct-to-VGPR.
// Wave w owns m-tiles {2w,2w+1}, all 8 n-tiles. 32 MFMA + 4 A-loads +
// 8 ds_read_b128 per kt; no barriers inside a phase.

__device__ __forceinline__ void store_a2(_Float16* __restrict__ A2, int m, int k, float v)
{
    const int mt2 = m >> 4, mr = m & 15;
    const int kt2 = k >> 5, kc = k & 31;
    const int l2 = (kc >> 3) * 16 + mr;
    const int j2 = kc & 7;
    const int mtb = mt2 >> 3, mts = mt2 & 7;
    const size_t idx = ((((size_t)mtb * 34 + kt2) * 8 + mts) * 64 + l2) * 8 + j2;
    A2[idx] = (_Float16)v;
}

__global__ __launch_bounds__(256, 2)
void gemm1_k(const _Float16* __restrict__ A, const _Float16* __restrict__ B,
             const float* __restrict__ bias, _Float16* __restrict__ A2)
{
    __shared__ _Float16 Bs[64 * 512];   // 64 KB: one phase = 8 kt x 8 n-tiles
    const int t = threadIdx.x, w = t >> 6, l = t & 63;

    // XCD-aware swizzle: 1152 blocks, 144 per XCD = 16 mblk x 9 bx
    // (bx fastest -> the 9 blocks sharing an A-panel are consecutive).
    const int lin = blockIdx.x;
    const int xcd = lin & 7, slot = lin >> 3;
    const int mblk = xcd * 16 + slot / 9;
    const int bx   = slot % 9;

    f32x4 acc[2][8];
#pragma unroll
    for (int i = 0; i < 2; ++i)
#pragma unroll
        for (int j = 0; j < 8; ++j) acc[i][j] = (f32x4)0.0f;

    const int lane8 = l * 8;
    const int w2 = 2 * w;
    // A tile (kt, mts) at ((mblk*32 + kt)*8 + mts)*512; Abase folds mblk, 2w, lane.
    const _Float16* Abase = A + ((size_t)mblk * 32 * 8 + w2) * 512 + lane8;
    const _Float16* Bpan  = B + (size_t)bx * 16 * 8 * 512;

    half8 ah[2][2], al[2][2];

    for (int ph = 0; ph < 2; ++ph) {
        const int ktb = ph * 8;
        __syncthreads();   // all waves done reading previous phase's Bs
        // stage 64 tiles (8 kt x 8 nt); wave w stages tiles w*16 .. w*16+15
#pragma unroll
        for (int i = 0; i < 16; ++i) {
            const int idx = w * 16 + i;   // idx = kt_local*8 + j
            stage16(Bpan + ((size_t)(ktb * 8 + idx)) * 512 + lane8, &Bs[(size_t)idx * 512]);
        }
        __syncthreads();   // staged data visible

        // A prologue for kt = ktb
#pragma unroll
        for (int i = 0; i < 2; ++i) {
            ah[0][i] = *(const half8*)(Abase + ((size_t)ktb * 8 + i) * 512);
            al[0][i] = *(const half8*)(Abase + ((size_t)(ktb + 16) * 8 + i) * 512);
        }

#pragma unroll
        for (int k = 0; k < 8; ++k) {
            const int s = k & 1;
            if (k + 1 < 8) {
                const int ktn = ktb + k + 1;
#pragma unroll
                for (int i = 0; i < 2; ++i) {
                    ah[s ^ 1][i] = *(const half8*)(Abase + ((size_t)ktn * 8 + i) * 512);
                    al[s ^ 1][i] = *(const half8*)(Abase + ((size_t)(ktn + 16) * 8 + i) * 512);
                }
            }
            half8 bh[8];
#pragma unroll
            for (int j = 0; j < 8; ++j)
                bh[j] = *(const half8*)&Bs[(size_t)(k * 8 + j) * 512 + lane8];
#pragma unroll
            for (int j = 0; j < 8; ++j) {
                acc[0][j] = __builtin_amdgcn_mfma_f32_16x16x32_f16(ah[s][0], bh[j], acc[0][j], 0, 0, 0);
                acc[1][j] = __builtin_amdgcn_mfma_f32_16x16x32_f16(ah[s][1], bh[j], acc[1][j], 0, 0, 0);
                acc[0][j] = __builtin_amdgcn_mfma_f32_16x16x32_f16(al[s][0], bh[j], acc[0][j], 0, 0, 0);
                acc[1][j] = __builtin_amdgcn_mfma_f32_16x16x32_f16(al[s][1], bh[j], acc[1][j], 0, 0, 0);
            }
        }
    }

    // epilogue: activation + swizzled fp16 stores (identical to round 6)
    const int r4 = (l >> 4) * 4, c16 = l & 15;
#pragma unroll
    for (int mt = 0; mt < 2; ++mt) {
        const int mbase = mblk * 128 + (w2 + mt) * 16 + r4;
#pragma unroll
        for (int nt = 0; nt < 4; ++nt) {
            const int c = bx * 64 + nt * 16 + c16;
            const bool valid = (c < 513);
            const float bm = valid ? bias[c] : 0.0f;
            const float bp = valid ? bias[513 + c] : 0.0f;
#pragma unroll
            for (int r = 0; r < 4; ++r) {
                float Sr = 0.0f, Si = 0.0f;
                if (valid) {
                    const float mag = fminf(expf(acc[mt][nt][r] + bm), 100.0f);
                    const float ph  = acc[mt][nt + 4][r] + bp;
                    Sr = mag * cosf(ph);
                    Si = mag * sinf(ph);
                }
                if (c < 544) {
                    store_a2(A2, mbase + r, c, Sr);
                    store_a2(A2, mbase + r, 544 + c, Si);
                }
            }
        }
    }
}

// ---------------- GEMM2: mirror-symmetric frames = A2 @ basis ---------------
// Hybrid: B staged in 4 phases (9/8/9/8 kt x 6 tiles, <=54 KB); A direct.
// Wave w owns m-tiles {2w,2w+1} x all 6 n-tiles (A loads wave-exclusive).
// Phase boundary at kt=17 aligns with the accC -> accD switch.

template<int LEN>
__device__ __forceinline__ void g2_phase(const _Float16* __restrict__ Abase,
                                         const _Float16* __restrict__ Bpan,
                                         _Float16* __restrict__ Bs,
                                         int k0, int w, int lane8,
                                         f32x4 (&acc)[2][6])
{
    __syncthreads();   // all waves done reading previous phase's Bs
    constexpr int CNT = LEN * 6;
#pragma unroll
    for (int i = 0; i < (CNT + 3) / 4; ++i) {
        const int idx = i * 4 + w;        // idx = kt_local*6 + nt
        if (idx < CNT)
            stage16(Bpan + ((size_t)(k0 * 6 + idx)) * 512 + lane8, &Bs[(size_t)idx * 512]);
    }
    __syncthreads();   // staged data visible

    half8 a[2][2];
#pragma unroll
    for (int i = 0; i < 2; ++i)
        a[0][i] = *(const half8*)(Abase + ((size_t)k0 * 8 + i) * 512);

#pragma unroll
    for (int k = 0; k < LEN; ++k) {
        const int s = k & 1;
        if (k + 1 < LEN) {
#pragma unroll
            for (int i = 0; i < 2; ++i)
                a[s ^ 1][i] = *(const half8*)(Abase + ((size_t)(k0 + k + 1) * 8 + i) * 512);
        }
        half8 b[6];
#pragma unroll
        for (int j = 0; j < 6; ++j)
            b[j] = *(const half8*)&Bs[(size_t)(k * 6 + j) * 512 + lane8];
#pragma unroll
        for (int i = 0; i < 2; ++i)
#pragma unroll
            for (int j = 0; j < 6; ++j)
                acc[i][j] = __builtin_amdgcn_mfma_f32_16x16x32_f16(a[s][i], b[j], acc[i][j], 0, 0, 0);
    }
}

__global__ __launch_bounds__(256, 2)
void gemm2_k(const _Float16* __restrict__ A, const _Float16* __restrict__ Bas,
             _Float16* __restrict__ C)
{
    __shared__ _Float16 Bs[54 * 512];   // 54 KB max phase (9 kt x 6 n-tiles)
    const int t = threadIdx.x, w = t >> 6, l = t & 63;

    // XCD-aware swizzle: 768 blocks, 96 per XCD = 16 mblk x 6 nblk
    // (nblk fastest -> the 6 blocks sharing an A2 panel are consecutive).
    const int lin = blockIdx.x;
    const int xcd = lin & 7, slot = lin >> 3;
    const int mblk = xcd * 16 + slot / 6;   // [0,128)
    const int nblk = slot % 6;              // [0,6)

    f32x4 accC[2][6], accD[2][6];
#pragma unroll
    for (int i = 0; i < 2; ++i)
#pragma unroll
        for (int j = 0; j < 6; ++j) { accC[i][j] = (f32x4)0.0f; accD[i][j] = (f32x4)0.0f; }

    const int lane8 = l * 8;
    const int w2 = 2 * w;
    // A tile (kt, mts) at ((mblk*34 + kt)*8 + mts)*512; Abase folds mblk, 2w, lane.
    const _Float16* Abase = A + ((size_t)mblk * 34 * 8 + w2) * 512 + lane8;
    const _Float16* Bpan  = Bas + (size_t)nblk * 34 * 6 * 512;

    g2_phase<9>(Abase, Bpan, Bs, 0,  w, lane8, accC);
    g2_phase<8>(Abase, Bpan, Bs, 9,  w, lane8, accC);
    g2_phase<9>(Abase, Bpan, Bs, 17, w, lane8, accD);
    g2_phase<8>(Abase, Bpan, Bs, 26, w, lane8, accD);

    // epilogue: frames[n] = C+D, frames[1024-n] = C-D (hann(1024-n)=hann(n))
    const int r4 = (l >> 4) * 4, c0 = l & 15;
#pragma unroll
    for (int i = 0; i < 2; ++i) {
        const int m = mblk * 128 + (w2 + i) * 16 + r4;
#pragma unroll
        for (int j = 0; j < 6; ++j) {
            const int n = nblk * 96 + j * 16 + c0;
#pragma unroll
            for (int r = 0; r < 4; ++r) {
                const float cv = accC[i][j][r];
                const float dv = accD[i][j][r];
                _Float16* row = C + (size_t)(m + r) * 1024;
                if (n < 513)           row[n]        = (_Float16)(cv + dv);
                if (n >= 1 && n < 512) row[1024 - n] = (_Float16)(cv - dv);
            }
        }
    }
}

// ---------------- overlap-add + envelope ------------------------------------

__global__ __launch_bounds__(256)
void ola_kernel(const _Float16* __restrict__ frames, float* __restrict__ out)
{
    const int idx = blockIdx.x * 256 + threadIdx.x;   // over 8 * 524288
    const int b = idx >> 19;
    const int j = idx & 524287;
    const int n = j + 384;

    int t_hi = n >> 8;
    if (t_hi > 2047) t_hi = 2047;
    const int t_lo = (n >= 1023) ? ((n - 1023 + 255) >> 8) : 0;

    float acc = 0.0f, env = 0.0f;
    for (int tt = t_lo; tt <= t_hi; ++tt) {
        const int s = n - (tt << 8);
        const float wv = hannf(s);
        acc += (float)frames[(((size_t)(b * 2048 + tt)) << 10) + s];
        env += wv * wv;
    }
    out[idx] = acc / env;
}

// ---------------- launch ----------------------------------------------------

extern "C" void kernel_launch(void* const* d_in, const int* in_sizes, int n_in,
                              void* d_out, int out_size, void* d_ws, size_t ws_size,
                              hipStream_t stream)
{
    const float* x = (const float*)d_in[0];   // 16384 x 512
    const float* W = (const float*)d_in[1];   // 512 x 1026
    const float* b = (const float*)d_in[2];   // 1026
    float* out = (float*)d_out;               // 8 x 524288
    char* ws = (char*)d_ws;

    _Float16* A2 = (_Float16*)(ws + OFF_A2);
    _Float16* B2 = (_Float16*)(ws + OFF_B2);
    _Float16* A1 = (_Float16*)(ws + OFF_A1);
    _Float16* B1 = (_Float16*)(ws + OFF_B1);
    _Float16* frames = (_Float16*)(ws + OFF_FR);

    conv_x_k<<<8192, 256, 0, stream>>>(x, A1);
    conv_w_k<<<288, 256, 0, stream>>>(W, B1);
    basis_k<<<306, 256, 0, stream>>>(B2);

    gemm1_k<<<1152, 256, 0, stream>>>(A1, B1, b, A2);
    gemm2_k<<<768, 256, 0, stream>>>(A2, B2, frames);

    ola_kernel<<<out_size / 256, 256, 0, stream>>>(frames, out);
}

// Round 9
// 229.155 us; speedup vs baseline: 1.3184x; 1.0120x over previous
//
#include <hip/hip_runtime.h>
#include <math.h>

// ---------------------------------------------------------------------------
// ISTFTHead on gfx950 — fp16 MFMA path, round 9.
//
// Round-8 post-mortem: all r3-r8 variants stall on load latency at each
// staging point (stage -> wait -> consume distance ~0); barrier count was
// never the lever. Round 9 = r6's exact staging/addressing with the K-loop
// reordered into a TRUE double-buffered prefetch, one barrier per step:
//     __syncthreads();         // drains buf[s] stages issued a FULL step ago
//     stage(buf[s^1], kt+1);   // prefetch, in flight across the whole mma
//     mma(buf[s]);
// The vmcnt(0) in __syncthreads now waits on loads that had an entire step
// to land -> cheap. Race-free: buf[s^1] was last read in step kt-1; all
// ds_read results are consumed by MFMAs before any wave reaches this step's
// barrier; the overwrite is issued after it.
//   gemm1: 16 steps x 24 KB, dbuf 48 KB, lb(256,3) -> 3 blocks/CU.
//   gemm2: 17 steps x 28 KB (2 kt), dbuf 56 KB, lb(256,2) -> 2 blocks/CU.
// conv/basis/ola and all epilogues byte-identical to round 6.
//
// Fragment order for mfma_f32_16x16x32_f16 (verified rounds 2-6):
//   A tile: elem(lane,j) = A[m = lane&15][k = (lane>>4)*8 + j]
//   B tile: elem(lane,j) = B[k = (lane>>4)*8 + j][n = lane&15]
//   C/D:    row = (lane>>4)*4 + r, col = lane&15
//   lane fragment = 16 B at tile_base + lane*16.
//
// Workspace map (bytes):
//   A2  [0,          35651584)   16384 x 1088 f16, [mb128][kt34][mts8][l][j]
//                                kt 0..16 = Sr rows, 17..33 = Si rows
//   B2  [35651584,   36904960)   mirror basis, [nblk6][kt34][nt6][l][j]
//   A1  [37879808,   71434240)   [xh|xl],      [mblk128][kt32][mts8][l][j]
//   B1  [71434240,   72613888)   Wh,           [bx9][kt16][t8][l][j]
//   frames [37879808, 71434240)  16384 x 1024 f16 (aliases A1 — dead by GEMM2)
// ---------------------------------------------------------------------------

using half8 = __attribute__((ext_vector_type(8))) _Float16;
using f32x4 = __attribute__((ext_vector_type(4))) float;

#define TWO_PI_OVER_1024 0.006135923151542565f

#define OFF_A2 0
#define OFF_B2 35651584UL
#define OFF_A1 37879808UL
#define OFF_B1 71434240UL
#define OFF_FR 37879808UL

__device__ __forceinline__ float hannf(int s) {
    return 0.5f * (1.0f - cosf(TWO_PI_OVER_1024 * (float)s));
}

// async global->LDS, 16B per lane. Global addr per-lane; LDS dest wave-uniform.
__device__ __forceinline__ void stage16(const void* g, void* lds) {
    __builtin_amdgcn_global_load_lds(
        (const __attribute__((address_space(1))) void*)g,
        (__attribute__((address_space(3))) void*)lds,
        16, 0, 0);
}

// ---------------- conversion kernels ----------------

// x (16384x512 f32) -> A1 fragment-swizzled fp16 [xh (kt 0..15) | xl (kt 16..31)]
__global__ __launch_bounds__(256)
void conv_x_k(const float* __restrict__ x, _Float16* __restrict__ A1)
{
    const size_t tid = (size_t)blockIdx.x * 256 + threadIdx.x;   // 2,097,152
    const int l   = (int)(tid & 63);
    const size_t f = tid >> 6;
    const int mts = (int)(f & 7);
    const size_t g = f >> 3;
    const int kt  = (int)(g & 31);
    const int mtb = (int)(g >> 5);
    const int m   = mtb * 128 + mts * 16 + (l & 15);
    const int k0  = (kt & 15) * 32 + (l >> 4) * 8;
    const bool hi = (kt < 16);
    const float* xp = x + (size_t)m * 512 + k0;
    const float4 v0 = *(const float4*)xp;
    const float4 v1 = *(const float4*)(xp + 4);
    const float vv[8] = {v0.x, v0.y, v0.z, v0.w, v1.x, v1.y, v1.z, v1.w};
    half8 o;
#pragma unroll
    for (int j = 0; j < 8; ++j) {
        _Float16 h = (_Float16)vv[j];
        o[j] = hi ? h : (_Float16)(vv[j] - (float)h);
    }
    *(half8*)(A1 + tid * 8) = o;
}

// W (512x1026 f32) -> B1 (Wh only) fragment-swizzled fp16, per bx(0..8):
// tiles 0..3 = mag cols (bx*64..+63), tiles 4..7 = phase cols (513 + same).
__global__ __launch_bounds__(256)
void conv_w_k(const float* __restrict__ W, _Float16* __restrict__ B1)
{
    const int tid = blockIdx.x * 256 + threadIdx.x;              // 73,728
    const int l  = tid & 63;
    const int f  = tid >> 6;
    const int t8 = f & 7;
    const int g  = f >> 3;
    const int kt = g & 15;
    const int bx = g >> 4;
    const int side = t8 >> 2;
    const int nt   = t8 & 3;
    const int c    = bx * 64 + nt * 16 + (l & 15);               // [0,576)
    const int k0   = kt * 32 + (l >> 4) * 8;
    const int wcol = side ? (513 + c) : c;
    half8 o;
#pragma unroll
    for (int j = 0; j < 8; ++j) {
        float v = (c < 513) ? W[(size_t)(k0 + j) * 1026 + wcol] : 0.0f;
        o[j] = (_Float16)v;
    }
    *(half8*)(B1 + (size_t)tid * 8) = o;
}

// Mirror-symmetric windowed irfft basis, n in [0,576), fragment order
// [nblk6][kt34][nt6][l][j]. kk = kt*32 + (l>>4)*8 + j:
//   kk < 544 : cos row for bin kk   (pairs with Sr)
//   kk >= 544: -sin row for bin kk-544 (pairs with Si)
// 78,336 threads = 306 blocks (threads = half8 count, NOT half count).
__global__ __launch_bounds__(256)
void basis_k(_Float16* __restrict__ B2)
{
    const int tid = blockIdx.x * 256 + threadIdx.x;              // 78,336
    const int l  = tid & 63;
    const int f  = tid >> 6;
    const int nt = f % 6;
    const int g  = f / 6;
    const int kt = g % 34;
    const int nblk = g / 34;
    const int n  = nblk * 96 + nt * 16 + (l & 15);
    const int kk0 = kt * 32 + (l >> 4) * 8;
    const float win = hannf(n) * (1.0f / 1024.0f);
    half8 o;
#pragma unroll
    for (int j = 0; j < 8; ++j) {
        const int kk = kk0 + j;
        float v = 0.0f;
        if (kk < 544) {
            const int k = kk;
            if (k < 513) {
                const float coef = (k == 0 || k == 512) ? 1.0f : 2.0f;
                v = coef * cosf(TWO_PI_OVER_1024 * (float)((k * n) & 1023)) * win;
            }
        } else {
            const int k = kk - 544;
            if (k < 513) {
                const float coef = (k == 0 || k == 512) ? 1.0f : 2.0f;
                v = -coef * sinf(TWO_PI_OVER_1024 * (float)((k * n) & 1023)) * win;
            }
        }
        o[j] = (_Float16)v;
    }
    *(half8*)(B2 + (size_t)tid * 8) = o;
}

// ---------------- GEMM1: x@W + b, fused activation, swizzled A2 output ------
// Double-buffered prefetch, one barrier per step, 16 steps of 1 kt.
// Per step per wave: 6 stage16 (prefetch) + 12 ds_read_b128 + 32 MFMA.

__device__ __forceinline__ void store_a2(_Float16* __restrict__ A2, int m, int k, float v)
{
    const int mt2 = m >> 4, mr = m & 15;
    const int kt2 = k >> 5, kc = k & 31;
    const int l2 = (kc >> 3) * 16 + mr;
    const int j2 = kc & 7;
    const int mtb = mt2 >> 3, mts = mt2 & 7;
    const size_t idx = ((((size_t)mtb * 34 + kt2) * 8 + mts) * 64 + l2) * 8 + j2;
    A2[idx] = (_Float16)v;
}

__global__ __launch_bounds__(256, 3)
void gemm1_k(const _Float16* __restrict__ A, const _Float16* __restrict__ B,
             const float* __restrict__ bias, _Float16* __restrict__ A2)
{
    __shared__ _Float16 Ash[2][8 * 512];
    __shared__ _Float16 Asl[2][8 * 512];
    __shared__ _Float16 Bsh[2][8 * 512];
    const int t = threadIdx.x, w = t >> 6, l = t & 63;

    // XCD-aware swizzle: 1152 blocks, 144 per XCD = 16 mblk x 9 bx.
    const int lin = blockIdx.x;
    const int xcd = lin & 7, slot = lin >> 3;
    const int mblk = xcd * 16 + slot / 9;
    const int bx   = slot % 9;

    f32x4 acc[2][8];
#pragma unroll
    for (int i = 0; i < 2; ++i)
#pragma unroll
        for (int j = 0; j < 8; ++j) acc[i][j] = (f32x4)0.0f;

    const _Float16* Ab = A + (size_t)mblk * (32 * 4096);
    const _Float16* Bb = B + (size_t)bx * (16 * 4096);
    const int lane8 = l * 8;
    const int w2 = 2 * w;

    // prologue: stage kt=0 into buf 0
    {
        const _Float16* Agh = Ab + w2 * 512 + lane8;
        const _Float16* Agl = Agh + 16 * 4096;
        const _Float16* Bgh = Bb + w2 * 512 + lane8;
        stage16(Agh,       &Ash[0][w2 * 512]);
        stage16(Agh + 512, &Ash[0][(w2 + 1) * 512]);
        stage16(Agl,       &Asl[0][w2 * 512]);
        stage16(Agl + 512, &Asl[0][(w2 + 1) * 512]);
        stage16(Bgh,       &Bsh[0][w2 * 512]);
        stage16(Bgh + 512, &Bsh[0][(w2 + 1) * 512]);
    }

#pragma unroll
    for (int kt = 0; kt < 16; ++kt) {
        const int s = kt & 1;
        __syncthreads();               // buf[s] ready (staged a full step ago)
        if (kt + 1 < 16) {             // prefetch buf[s^1] — in flight across mma
            const int kn = kt + 1;
            const _Float16* Agh = Ab + (size_t)kn * 4096 + w2 * 512 + lane8;
            const _Float16* Agl = Agh + 16 * 4096;
            const _Float16* Bgh = Bb + (size_t)kn * 4096 + w2 * 512 + lane8;
            stage16(Agh,       &Ash[s ^ 1][w2 * 512]);
            stage16(Agh + 512, &Ash[s ^ 1][(w2 + 1) * 512]);
            stage16(Agl,       &Asl[s ^ 1][w2 * 512]);
            stage16(Agl + 512, &Asl[s ^ 1][(w2 + 1) * 512]);
            stage16(Bgh,       &Bsh[s ^ 1][w2 * 512]);
            stage16(Bgh + 512, &Bsh[s ^ 1][(w2 + 1) * 512]);
        }

        half8 ah[2], al[2];
#pragma unroll
        for (int i = 0; i < 2; ++i) {
            ah[i] = *(const half8*)&Ash[s][(w2 + i) * 512 + lane8];
            al[i] = *(const half8*)&Asl[s][(w2 + i) * 512 + lane8];
        }
#pragma unroll
        for (int j = 0; j < 8; ++j) {
            const half8 bh = *(const half8*)&Bsh[s][j * 512 + lane8];
            acc[0][j] = __builtin_amdgcn_mfma_f32_16x16x32_f16(ah[0], bh, acc[0][j], 0, 0, 0);
            acc[1][j] = __builtin_amdgcn_mfma_f32_16x16x32_f16(ah[1], bh, acc[1][j], 0, 0, 0);
            acc[0][j] = __builtin_amdgcn_mfma_f32_16x16x32_f16(al[0], bh, acc[0][j], 0, 0, 0);
            acc[1][j] = __builtin_amdgcn_mfma_f32_16x16x32_f16(al[1], bh, acc[1][j], 0, 0, 0);
        }
    }

    // epilogue: activation + swizzled fp16 stores (identical to round 6)
    const int r4 = (l >> 4) * 4, c16 = l & 15;
#pragma unroll
    for (int mt = 0; mt < 2; ++mt) {
        const int mbase = mblk * 128 + (w2 + mt) * 16 + r4;
#pragma unroll
        for (int nt = 0; nt < 4; ++nt) {
            const int c = bx * 64 + nt * 16 + c16;
            const bool valid = (c < 513);
            const float bm = valid ? bias[c] : 0.0f;
            const float bp = valid ? bias[513 + c] : 0.0f;
#pragma unroll
            for (int r = 0; r < 4; ++r) {
                float Sr = 0.0f, Si = 0.0f;
                if (valid) {
                    const float mag = fminf(expf(acc[mt][nt][r] + bm), 100.0f);
                    const float ph  = acc[mt][nt + 4][r] + bp;
                    Sr = mag * cosf(ph);
                    Si = mag * sinf(ph);
                }
                if (c < 544) {
                    store_a2(A2, mbase + r, c, Sr);
                    store_a2(A2, mbase + r, 544 + c, Si);
                }
            }
        }
    }
}

// ---------------- GEMM2: mirror-symmetric frames = A2 @ basis ---------------
// Double-buffered prefetch, one barrier per step, 17 steps of 2 kt.
// Tile layout in LDS: A tiles indexed ta = u*8 + mts (16/buf), B tiles
// tb = u*6 + nt (12/buf). kt<17 -> accC (cos/Sr), kt>=17 -> accD (sin/Si).

__device__ __forceinline__ void g2_stage(const _Float16* __restrict__ A,
                                         const _Float16* __restrict__ Bas,
                                         _Float16* __restrict__ As,
                                         _Float16* __restrict__ Bs,
                                         int mblk, int nblk, int kt0,
                                         int w, int lane8)
{
#pragma unroll
    for (int i = 0; i < 4; ++i) {
        const int ta = 4 * w + i;
        const int u = ta >> 3, mts = ta & 7;
        const _Float16* Ag = A + ((((size_t)mblk * 34 + (kt0 + u)) * 8 + mts) * 512) + lane8;
        stage16(Ag, &As[(size_t)ta * 512]);
    }
#pragma unroll
    for (int i = 0; i < 3; ++i) {
        const int tb = 3 * w + i;
        const int u = tb / 6, nt = tb % 6;
        const _Float16* Bg = Bas + ((((size_t)nblk * 34 + (kt0 + u)) * 6 + nt) * 512) + lane8;
        stage16(Bg, &Bs[(size_t)tb * 512]);
    }
}

__global__ __launch_bounds__(256, 2)
void gemm2_k(const _Float16* __restrict__ A, const _Float16* __restrict__ Bas,
             _Float16* __restrict__ C)
{
    __shared__ _Float16 As[2][16 * 512];   // 16 KB per buffer
    __shared__ _Float16 Bs[2][12 * 512];   // 12 KB per buffer  (total 56 KB)
    const int t = threadIdx.x, w = t >> 6, l = t & 63;

    // XCD-aware swizzle: 768 blocks, 96 per XCD = 16 mblk x 6 nblk.
    const int lin = blockIdx.x;
    const int xcd = lin & 7, slot = lin >> 3;
    const int mblk = xcd * 16 + slot / 6;   // [0,128)
    const int nblk = slot % 6;              // [0,6)

    const int wm = (w & 1) * 4, wn = (w >> 1) * 3;

    f32x4 accC[4][3], accD[4][3];
#pragma unroll
    for (int i = 0; i < 4; ++i)
#pragma unroll
        for (int j = 0; j < 3; ++j) { accC[i][j] = (f32x4)0.0f; accD[i][j] = (f32x4)0.0f; }

    const int lane8 = l * 8;

    g2_stage(A, Bas, As[0], Bs[0], mblk, nblk, 0, w, lane8);   // prologue

#pragma unroll
    for (int step = 0; step < 17; ++step) {
        const int s = step & 1;
        __syncthreads();               // buf[s] ready (staged a full step ago)
        if (step + 1 < 17)             // prefetch buf[s^1]
            g2_stage(A, Bas, As[s ^ 1], Bs[s ^ 1], mblk, nblk, 2 * (step + 1), w, lane8);

#pragma unroll
        for (int u = 0; u < 2; ++u) {
            const int kt = 2 * step + u;
            half8 a[4], b[3];
#pragma unroll
            for (int i = 0; i < 4; ++i)
                a[i] = *(const half8*)&As[s][(size_t)(u * 8 + wm + i) * 512 + lane8];
#pragma unroll
            for (int j = 0; j < 3; ++j)
                b[j] = *(const half8*)&Bs[s][(size_t)(u * 6 + wn + j) * 512 + lane8];
            if (kt < 17) {
#pragma unroll
                for (int i = 0; i < 4; ++i)
#pragma unroll
                    for (int j = 0; j < 3; ++j)
                        accC[i][j] = __builtin_amdgcn_mfma_f32_16x16x32_f16(a[i], b[j], accC[i][j], 0, 0, 0);
            } else {
#pragma unroll
                for (int i = 0; i < 4; ++i)
#pragma unroll
                    for (int j = 0; j < 3; ++j)
                        accD[i][j] = __builtin_amdgcn_mfma_f32_16x16x32_f16(a[i], b[j], accD[i][j], 0, 0, 0);
            }
        }
    }

    // epilogue: frames[n] = C+D, frames[1024-n] = C-D  (hann(1024-n)=hann(n))
    const int r4 = (l >> 4) * 4, c0 = l & 15;
#pragma unroll
    for (int i = 0; i < 4; ++i) {
        const int m = mblk * 128 + (wm + i) * 16 + r4;
#pragma unroll
        for (int j = 0; j < 3; ++j) {
            const int n = nblk * 96 + (wn + j) * 16 + c0;
#pragma unroll
            for (int r = 0; r < 4; ++r) {
                const float cv = accC[i][j][r];
                const float dv = accD[i][j][r];
                _Float16* row = C + (size_t)(m + r) * 1024;
                if (n < 513)           row[n]        = (_Float16)(cv + dv);
                if (n >= 1 && n < 512) row[1024 - n] = (_Float16)(cv - dv);
            }
        }
    }
}

// ---------------- overlap-add + envelope ------------------------------------

__global__ __launch_bounds__(256)
void ola_kernel(const _Float16* __restrict__ frames, float* __restrict__ out)
{
    const int idx = blockIdx.x * 256 + threadIdx.x;   // over 8 * 524288
    const int b = idx >> 19;
    const int j = idx & 524287;
    const int n = j + 384;

    int t_hi = n >> 8;
    if (t_hi > 2047) t_hi = 2047;
    const int t_lo = (n >= 1023) ? ((n - 1023 + 255) >> 8) : 0;

    float acc = 0.0f, env = 0.0f;
    for (int tt = t_lo; tt <= t_hi; ++tt) {
        const int s = n - (tt << 8);
        const float wv = hannf(s);
        acc += (float)frames[(((size_t)(b * 2048 + tt)) << 10) + s];
        env += wv * wv;
    }
    out[idx] = acc / env;
}

// ---------------- launch ----------------------------------------------------

extern "C" void kernel_launch(void* const* d_in, const int* in_sizes, int n_in,
                              void* d_out, int out_size, void* d_ws, size_t ws_size,
                              hipStream_t stream)
{
    const float* x = (const float*)d_in[0];   // 16384 x 512
    const float* W = (const float*)d_in[1];   // 512 x 1026
    const float* b = (const float*)d_in[2];   // 1026
    float* out = (float*)d_out;               // 8 x 524288
    char* ws = (char*)d_ws;

    _Float16* A2 = (_Float16*)(ws + OFF_A2);
    _Float16* B2 = (_Float16*)(ws + OFF_B2);
    _Float16* A1 = (_Float16*)(ws + OFF_A1);
    _Float16* B1 = (_Float16*)(ws + OFF_B1);
    _Float16* frames = (_Float16*)(ws + OFF_FR);

    conv_x_k<<<8192, 256, 0, stream>>>(x, A1);
    conv_w_k<<<288, 256, 0, stream>>>(W, B1);
    basis_k<<<306, 256, 0, stream>>>(B2);

    gemm1_k<<<1152, 256, 0, stream>>>(A1, B1, b, A2);
    gemm2_k<<<768, 256, 0, stream>>>(A2, B2, frames);

    ola_kernel<<<out_size / 256, 256, 0, stream>>>(frames, out);
}

// Round 10
// 194.785 us; speedup vs baseline: 1.5510x; 1.1765x over previous
//
#include <hip/hip_runtime.h>
#include <math.h>

// ---------------------------------------------------------------------------
// ISTFTHead on gfx950 — fp16 MFMA path, round 10.
//
// Round-9 post-mortem: dbuf/barrier/occupancy tuning is exhausted (m97
// plateau, ~20% MfmaUtil). Round 10 reduces work + rebalances waves:
//  * GEMM1 single fp16 product (xh@Wh only). Dropping xl adds h-err ~7e-4,
//    1.5x the already-invisible W-rounding err from r4; absmax unchanged.
//    Halves gemm1 MFMA/staging and conv_x writes.
//  * GEMM1 wave grid 2x2 (4 m-tiles x 4 n-tiles/wave, mag+phase tiles
//    paired per wave): per-kt LDS reads 12->8 KB/wave; LDS time ~ MFMA time.
//  * conv_w + basis merged into one launch (one less ~7us gap).
//  * GEMM2 byte-identical to round 6 (best measured variant).
//
// Fragment order for mfma_f32_16x16x32_f16 (verified rounds 2-9):
//   A tile: elem(lane,j) = A[m = lane&15][k = (lane>>4)*8 + j]
//   B tile: elem(lane,j) = B[k = (lane>>4)*8 + j][n = lane&15]
//   C/D:    row = (lane>>4)*4 + r, col = lane&15
//   lane fragment = 16 B at tile_base + lane*16.
//
// Workspace map (bytes):
//   A2  [0,          35651584)   16384 x 1088 f16, [mb128][kt34][mts8][l][j]
//                                k<544 = Sr, k>=544 = Si
//   B2  [35651584,   36904960)   mirror basis, [nblk6][kt34][nt6][l][j]
//   A1  [37879808,   54657024)   xh,  [mblk128][kt16][mts8][l][j]  (16.8 MB)
//   B1  [54657024,   55836672)   Wh,  [bx9][kt16][t8][l][j]
//   frames [37879808, 71434240)  16384 x 1024 f16 (overlays A1+B1 — both
//                                dead once gemm2 runs; A2/B2 untouched)
// ---------------------------------------------------------------------------

using half8 = __attribute__((ext_vector_type(8))) _Float16;
using f32x4 = __attribute__((ext_vector_type(4))) float;

#define TWO_PI_OVER_1024 0.006135923151542565f

#define OFF_A2 0
#define OFF_B2 35651584UL
#define OFF_A1 37879808UL
#define OFF_B1 54657024UL
#define OFF_FR 37879808UL

__device__ __forceinline__ float hannf(int s) {
    return 0.5f * (1.0f - cosf(TWO_PI_OVER_1024 * (float)s));
}

// async global->LDS, 16B per lane. Global addr per-lane; LDS dest wave-uniform.
__device__ __forceinline__ void stage16(const void* g, void* lds) {
    __builtin_amdgcn_global_load_lds(
        (const __attribute__((address_space(1))) void*)g,
        (__attribute__((address_space(3))) void*)lds,
        16, 0, 0);
}

// ---------------- conversion kernels ----------------

// x (16384x512 f32) -> A1 fragment-swizzled fp16 (xh only, 16 kt).
// 1,048,576 threads = 4096 blocks.
__global__ __launch_bounds__(256)
void conv_x_k(const float* __restrict__ x, _Float16* __restrict__ A1)
{
    const size_t tid = (size_t)blockIdx.x * 256 + threadIdx.x;   // 1,048,576
    const int l   = (int)(tid & 63);
    const size_t f = tid >> 6;
    const int mts = (int)(f & 7);
    const size_t g = f >> 3;
    const int kt  = (int)(g & 15);
    const int mtb = (int)(g >> 4);
    const int m   = mtb * 128 + mts * 16 + (l & 15);
    const int k0  = kt * 32 + (l >> 4) * 8;
    const float* xp = x + (size_t)m * 512 + k0;
    const float4 v0 = *(const float4*)xp;
    const float4 v1 = *(const float4*)(xp + 4);
    const float vv[8] = {v0.x, v0.y, v0.z, v0.w, v1.x, v1.y, v1.z, v1.w};
    half8 o;
#pragma unroll
    for (int j = 0; j < 8; ++j) o[j] = (_Float16)vv[j];
    *(half8*)(A1 + tid * 8) = o;
}

// Merged prep kernel: blocks [0,288) -> conv_w; blocks [288,594) -> basis.
__global__ __launch_bounds__(256)
void prep_k(const float* __restrict__ W, _Float16* __restrict__ B1,
            _Float16* __restrict__ B2)
{
    if (blockIdx.x < 288) {
        // W (512x1026 f32) -> B1 (Wh only), per bx(0..8):
        // tiles 0..3 = mag cols (bx*64..+63), 4..7 = phase cols (513 + same).
        const int tid = blockIdx.x * 256 + threadIdx.x;          // 73,728
        const int l  = tid & 63;
        const int f  = tid >> 6;
        const int t8 = f & 7;
        const int g  = f >> 3;
        const int kt = g & 15;
        const int bx = g >> 4;
        const int side = t8 >> 2;
        const int nt   = t8 & 3;
        const int c    = bx * 64 + nt * 16 + (l & 15);           // [0,576)
        const int k0   = kt * 32 + (l >> 4) * 8;
        const int wcol = side ? (513 + c) : c;
        half8 o;
#pragma unroll
        for (int j = 0; j < 8; ++j) {
            float v = (c < 513) ? W[(size_t)(k0 + j) * 1026 + wcol] : 0.0f;
            o[j] = (_Float16)v;
        }
        *(half8*)(B1 + (size_t)tid * 8) = o;
    } else {
        // Mirror-symmetric windowed irfft basis, n in [0,576),
        // [nblk6][kt34][nt6][l][j]. kk<544: cos bin kk; kk>=544: -sin bin kk-544.
        const int tid = (blockIdx.x - 288) * 256 + threadIdx.x;  // 78,336
        const int l  = tid & 63;
        const int f  = tid >> 6;
        const int nt = f % 6;
        const int g  = f / 6;
        const int kt = g % 34;
        const int nblk = g / 34;
        const int n  = nblk * 96 + nt * 16 + (l & 15);
        const int kk0 = kt * 32 + (l >> 4) * 8;
        const float win = hannf(n) * (1.0f / 1024.0f);
        half8 o;
#pragma unroll
        for (int j = 0; j < 8; ++j) {
            const int kk = kk0 + j;
            float v = 0.0f;
            if (kk < 544) {
                const int k = kk;
                if (k < 513) {
                    const float coef = (k == 0 || k == 512) ? 1.0f : 2.0f;
                    v = coef * cosf(TWO_PI_OVER_1024 * (float)((k * n) & 1023)) * win;
                }
            } else {
                const int k = kk - 544;
                if (k < 513) {
                    const float coef = (k == 0 || k == 512) ? 1.0f : 2.0f;
                    v = -coef * sinf(TWO_PI_OVER_1024 * (float)((k * n) & 1023)) * win;
                }
            }
            o[j] = (_Float16)v;
        }
        *(half8*)(B2 + (size_t)tid * 8) = o;
    }
}

// ---------------- GEMM1: h = xh@Wh + b, fused activation -------------------
// Block 128m x 8 n-tiles (4 mag + 4 phase). Wave grid 2x2: wave w owns
// m-tiles wm..wm+3 (wm = (w&1)*4) and n-tiles {2q,2q+1, 4+2q,5+2q} (q=w>>1)
// so each wave holds matching mag+phase columns for the fused activation.
// 8 steps x 2 kt; per step per wave: 8 stage16, 16 ds_read_b128, 32 MFMA.

__device__ __forceinline__ void store_a2(_Float16* __restrict__ A2, int m, int k, float v)
{
    const int mt2 = m >> 4, mr = m & 15;
    const int kt2 = k >> 5, kc = k & 31;
    const int l2 = (kc >> 3) * 16 + mr;
    const int j2 = kc & 7;
    const int mtb = mt2 >> 3, mts = mt2 & 7;
    const size_t idx = ((((size_t)mtb * 34 + kt2) * 8 + mts) * 64 + l2) * 8 + j2;
    A2[idx] = (_Float16)v;
}

__global__ __launch_bounds__(256, 3)
void gemm1_k(const _Float16* __restrict__ A, const _Float16* __restrict__ B,
             const float* __restrict__ bias, _Float16* __restrict__ A2)
{
    __shared__ _Float16 Ash[2][8 * 512];   // 2 kt x 8 m-tiles (16 KB)
    __shared__ _Float16 Bsh[2][8 * 512];   // 2 kt x 8 n-tiles (16 KB)
    const int t = threadIdx.x, w = t >> 6, l = t & 63;

    // XCD-aware swizzle: 1152 blocks, 144 per XCD = 16 mblk x 9 bx.
    const int lin = blockIdx.x;
    const int xcd = lin & 7, slot = lin >> 3;
    const int mblk = xcd * 16 + slot / 9;
    const int bx   = slot % 9;

    const int wm = (w & 1) * 4;            // m-tile base
    const int q  = w >> 1;                 // n-pair index
    const int jt[4] = {2 * q, 2 * q + 1, 4 + 2 * q, 5 + 2 * q};

    f32x4 acc[4][4];                       // [m-tile][0..1 mag | 2..3 phase]
#pragma unroll
    for (int i = 0; i < 4; ++i)
#pragma unroll
        for (int j = 0; j < 4; ++j) acc[i][j] = (f32x4)0.0f;

    const int lane8 = l * 8;
    const _Float16* Ab = A + ((size_t)mblk * 16 * 8) * 512 + lane8;
    const _Float16* Bb = B + ((size_t)bx * 16 * 8) * 512 + lane8;

    for (int step = 0; step < 8; ++step) {
        const int kt0 = 2 * step;
        __syncthreads();
        // stage 16 A slots + 16 B slots; wave w takes slots 4w..4w+3 of each
#pragma unroll
        for (int i = 0; i < 4; ++i) {
            const int s = 4 * w + i;
            const int u = s >> 3, r = s & 7;
            stage16(Ab + ((size_t)(kt0 + u) * 8 + r) * 512, &Ash[u][r * 512]);
            stage16(Bb + ((size_t)(kt0 + u) * 8 + r) * 512, &Bsh[u][r * 512]);
        }
        __syncthreads();

#pragma unroll
        for (int u = 0; u < 2; ++u) {
            half8 a[4], b[4];
#pragma unroll
            for (int i = 0; i < 4; ++i)
                a[i] = *(const half8*)&Ash[u][(wm + i) * 512 + lane8];
#pragma unroll
            for (int j = 0; j < 4; ++j)
                b[j] = *(const half8*)&Bsh[u][jt[j] * 512 + lane8];
#pragma unroll
            for (int i = 0; i < 4; ++i)
#pragma unroll
                for (int j = 0; j < 4; ++j)
                    acc[i][j] = __builtin_amdgcn_mfma_f32_16x16x32_f16(a[i], b[j], acc[i][j], 0, 0, 0);
        }
    }

    // epilogue: activation + swizzled fp16 stores
    const int r4 = (l >> 4) * 4, c16 = l & 15;
#pragma unroll
    for (int i = 0; i < 4; ++i) {
        const int mbase = mblk * 128 + (wm + i) * 16 + r4;
#pragma unroll
        for (int p = 0; p < 2; ++p) {
            const int c = bx * 64 + (2 * q + p) * 16 + c16;   // [0,576)
            const bool valid = (c < 513);
            const float bm = valid ? bias[c] : 0.0f;
            const float bp = valid ? bias[513 + c] : 0.0f;
#pragma unroll
            for (int r = 0; r < 4; ++r) {
                float Sr = 0.0f, Si = 0.0f;
                if (valid) {
                    const float mag = fminf(expf(acc[i][p][r] + bm), 100.0f);
                    const float ph  = acc[i][2 + p][r] + bp;
                    Sr = mag * cosf(ph);
                    Si = mag * sinf(ph);
                }
                if (c < 544) {
                    store_a2(A2, mbase + r, c, Sr);
                    store_a2(A2, mbase + r, 544 + c, Si);
                }
            }
        }
    }
}

// ---------------- GEMM2: mirror-symmetric frames = A2 @ basis ---------------
// Byte-identical to round 6: 17 steps of 2 kt, stage-then-mma, lb(256,3).

__device__ __forceinline__ void mma43(const _Float16* __restrict__ As,
                                      const _Float16* __restrict__ Bs,
                                      int wm, int wn, int lane16, f32x4 (&acc)[4][3])
{
    half8 a[4], b[3];
#pragma unroll
    for (int i = 0; i < 4; ++i) a[i] = *(const half8*)&As[(wm + i) * 512 + lane16];
#pragma unroll
    for (int j = 0; j < 3; ++j) b[j] = *(const half8*)&Bs[(wn + j) * 512 + lane16];
#pragma unroll
    for (int i = 0; i < 4; ++i)
#pragma unroll
        for (int j = 0; j < 3; ++j)
            acc[i][j] = __builtin_amdgcn_mfma_f32_16x16x32_f16(a[i], b[j], acc[i][j], 0, 0, 0);
}

__global__ __launch_bounds__(256, 3)
void gemm2_k(const _Float16* __restrict__ A, const _Float16* __restrict__ Bas,
             _Float16* __restrict__ C)
{
    __shared__ _Float16 As[2][8 * 512];   // 2 k-tiles x 128 m-rows
    __shared__ _Float16 Bs[2][6 * 512];   // 2 k-tiles x 96 n-cols
    const int t = threadIdx.x, w = t >> 6, l = t & 63;

    // XCD-aware swizzle: 768 blocks, 96 per XCD = 16 mblk x 6 nblk.
    const int lin = blockIdx.x;
    const int xcd = lin & 7, slot = lin >> 3;
    const int mblk = xcd * 16 + slot / 6;   // [0,128)
    const int nblk = slot % 6;              // [0,6)

    const int wm = (w & 1) * 4, wn = (w >> 1) * 3;

    f32x4 accC[4][3], accD[4][3];
#pragma unroll
    for (int i = 0; i < 4; ++i)
#pragma unroll
        for (int j = 0; j < 3; ++j) { accC[i][j] = (f32x4)0.0f; accD[i][j] = (f32x4)0.0f; }

    const int lane16 = l * 8;

    for (int step = 0; step < 17; ++step) {
        const int kt0 = 2 * step;
        __syncthreads();
#pragma unroll
        for (int i = 0; i < 4; ++i) {
            const int ta = 4 * w + i;
            const int u = ta >> 3, mts = ta & 7;
            const _Float16* Ag = A + ((((size_t)mblk * 34 + (kt0 + u)) * 8 + mts) * 512) + lane16;
            stage16(Ag, &As[u][mts * 512]);
        }
#pragma unroll
        for (int i = 0; i < 3; ++i) {
            const int tb = 3 * w + i;
            const int u = tb / 6, nt = tb % 6;
            const _Float16* Bg = Bas + ((((size_t)nblk * 34 + (kt0 + u)) * 6 + nt) * 512) + lane16;
            stage16(Bg, &Bs[u][nt * 512]);
        }
        __syncthreads();

#pragma unroll
        for (int u = 0; u < 2; ++u) {
            const int kt = kt0 + u;
            if (kt < 17) mma43(As[u], Bs[u], wm, wn, lane16, accC);
            else         mma43(As[u], Bs[u], wm, wn, lane16, accD);
        }
    }

    // epilogue: frames[n] = C+D, frames[1024-n] = C-D  (hann(1024-n)=hann(n))
    const int r4 = (l >> 4) * 4, c0 = l & 15;
#pragma unroll
    for (int i = 0; i < 4; ++i) {
        const int m = mblk * 128 + (wm + i) * 16 + r4;
#pragma unroll
        for (int j = 0; j < 3; ++j) {
            const int n = nblk * 96 + (wn + j) * 16 + c0;
#pragma unroll
            for (int r = 0; r < 4; ++r) {
                const float cv = accC[i][j][r];
                const float dv = accD[i][j][r];
                _Float16* row = C + (size_t)(m + r) * 1024;
                if (n < 513)           row[n]        = (_Float16)(cv + dv);
                if (n >= 1 && n < 512) row[1024 - n] = (_Float16)(cv - dv);
            }
        }
    }
}

// ---------------- overlap-add + envelope ------------------------------------

__global__ __launch_bounds__(256)
void ola_kernel(const _Float16* __restrict__ frames, float* __restrict__ out)
{
    const int idx = blockIdx.x * 256 + threadIdx.x;   // over 8 * 524288
    const int b = idx >> 19;
    const int j = idx & 524287;
    const int n = j + 384;

    int t_hi = n >> 8;
    if (t_hi > 2047) t_hi = 2047;
    const int t_lo = (n >= 1023) ? ((n - 1023 + 255) >> 8) : 0;

    float acc = 0.0f, env = 0.0f;
    for (int tt = t_lo; tt <= t_hi; ++tt) {
        const int s = n - (tt << 8);
        const float wv = hannf(s);
        acc += (float)frames[(((size_t)(b * 2048 + tt)) << 10) + s];
        env += wv * wv;
    }
    out[idx] = acc / env;
}

// ---------------- launch ----------------------------------------------------

extern "C" void kernel_launch(void* const* d_in, const int* in_sizes, int n_in,
                              void* d_out, int out_size, void* d_ws, size_t ws_size,
                              hipStream_t stream)
{
    const float* x = (const float*)d_in[0];   // 16384 x 512
    const float* W = (const float*)d_in[1];   // 512 x 1026
    const float* b = (const float*)d_in[2];   // 1026
    float* out = (float*)d_out;               // 8 x 524288
    char* ws = (char*)d_ws;

    _Float16* A2 = (_Float16*)(ws + OFF_A2);
    _Float16* B2 = (_Float16*)(ws + OFF_B2);
    _Float16* A1 = (_Float16*)(ws + OFF_A1);
    _Float16* B1 = (_Float16*)(ws + OFF_B1);
    _Float16* frames = (_Float16*)(ws + OFF_FR);

    conv_x_k<<<4096, 256, 0, stream>>>(x, A1);
    prep_k<<<594, 256, 0, stream>>>(W, B1, B2);

    gemm1_k<<<1152, 256, 0, stream>>>(A1, B1, b, A2);
    gemm2_k<<<768, 256, 0, stream>>>(A2, B2, frames);

    ola_kernel<<<out_size / 256, 256, 0, stream>>>(frames, out);
}

// Round 11
// 167.203 us; speedup vs baseline: 1.8069x; 1.1650x over previous
//
#include <hip/hip_runtime.h>
#include <math.h>

// ---------------------------------------------------------------------------
// ISTFTHead on gfx950 — fp16 MFMA path, round 11.
//
// Round-10 post-mortem: gemm1's fused activation epilogue (libm exp/cos/sin,
// ~4-5K cyc/wave) is ~4x its MFMA time; VALUBusy 36% vs MfmaUtil 13%.
// Round 11:
//  * __expf/__cosf/__sinf (HW v_exp/v_sin/v_cos) in gemm1 epilogue, hannf,
//    and basis trig — err ~2^-21, invisible vs the 2e-3 absmax.
//  * conv_x + conv_w + basis merged into ONE prep launch (4690 blocks).
//  * gemm1 launch_bounds(256,4) (VGPR 68 / LDS 32KB both allow 4 blocks/CU).
//  * gemm2 byte-identical to round 10 (= round 6 structure, best measured).
//
// Fragment order for mfma_f32_16x16x32_f16 (verified rounds 2-10):
//   A tile: elem(lane,j) = A[m = lane&15][k = (lane>>4)*8 + j]
//   B tile: elem(lane,j) = B[k = (lane>>4)*8 + j][n = lane&15]
//   C/D:    row = (lane>>4)*4 + r, col = lane&15
//   lane fragment = 16 B at tile_base + lane*16.
//
// Workspace map (bytes):
//   A2  [0,          35651584)   16384 x 1088 f16, [mb128][kt34][mts8][l][j]
//                                k<544 = Sr, k>=544 = Si
//   B2  [35651584,   36904960)   mirror basis, [nblk6][kt34][nt6][l][j]
//   A1  [37879808,   54657024)   xh,  [mblk128][kt16][mts8][l][j]
//   B1  [54657024,   55836672)   Wh,  [bx9][kt16][t8][l][j]
//   frames [37879808, 71434240)  16384 x 1024 f16 (overlays A1+B1 — dead by gemm2)
// ---------------------------------------------------------------------------

using half8 = __attribute__((ext_vector_type(8))) _Float16;
using f32x4 = __attribute__((ext_vector_type(4))) float;

#define TWO_PI_OVER_1024 0.006135923151542565f

#define OFF_A2 0
#define OFF_B2 35651584UL
#define OFF_A1 37879808UL
#define OFF_B1 54657024UL
#define OFF_FR 37879808UL

__device__ __forceinline__ float hannf(int s) {
    return 0.5f * (1.0f - __cosf(TWO_PI_OVER_1024 * (float)s));
}

// async global->LDS, 16B per lane. Global addr per-lane; LDS dest wave-uniform.
__device__ __forceinline__ void stage16(const void* g, void* lds) {
    __builtin_amdgcn_global_load_lds(
        (const __attribute__((address_space(1))) void*)g,
        (__attribute__((address_space(3))) void*)lds,
        16, 0, 0);
}

// ---------------- merged prep kernel ----------------
// blocks [0,4096)     : x -> A1 (xh fragments)
// blocks [4096,4384)  : W -> B1 (Wh fragments)
// blocks [4384,4690)  : windowed mirror irfft basis -> B2
__global__ __launch_bounds__(256)
void prep_k(const float* __restrict__ x, const float* __restrict__ W,
            _Float16* __restrict__ A1, _Float16* __restrict__ B1,
            _Float16* __restrict__ B2)
{
    const int bid = blockIdx.x;
    if (bid < 4096) {
        // x (16384x512 f32) -> A1, [mblk128][kt16][mts8][l][j]
        const size_t tid = (size_t)bid * 256 + threadIdx.x;      // 1,048,576
        const int l   = (int)(tid & 63);
        const size_t f = tid >> 6;
        const int mts = (int)(f & 7);
        const size_t g = f >> 3;
        const int kt  = (int)(g & 15);
        const int mtb = (int)(g >> 4);
        const int m   = mtb * 128 + mts * 16 + (l & 15);
        const int k0  = kt * 32 + (l >> 4) * 8;
        const float* xp = x + (size_t)m * 512 + k0;
        const float4 v0 = *(const float4*)xp;
        const float4 v1 = *(const float4*)(xp + 4);
        const float vv[8] = {v0.x, v0.y, v0.z, v0.w, v1.x, v1.y, v1.z, v1.w};
        half8 o;
#pragma unroll
        for (int j = 0; j < 8; ++j) o[j] = (_Float16)vv[j];
        *(half8*)(A1 + tid * 8) = o;
    } else if (bid < 4384) {
        // W (512x1026 f32) -> B1, per bx(0..8): tiles 0..3 mag, 4..7 phase.
        const int tid = (bid - 4096) * 256 + threadIdx.x;        // 73,728
        const int l  = tid & 63;
        const int f  = tid >> 6;
        const int t8 = f & 7;
        const int g  = f >> 3;
        const int kt = g & 15;
        const int bx = g >> 4;
        const int side = t8 >> 2;
        const int nt   = t8 & 3;
        const int c    = bx * 64 + nt * 16 + (l & 15);           // [0,576)
        const int k0   = kt * 32 + (l >> 4) * 8;
        const int wcol = side ? (513 + c) : c;
        half8 o;
#pragma unroll
        for (int j = 0; j < 8; ++j) {
            float v = (c < 513) ? W[(size_t)(k0 + j) * 1026 + wcol] : 0.0f;
            o[j] = (_Float16)v;
        }
        *(half8*)(B1 + (size_t)tid * 8) = o;
    } else {
        // basis -> B2, [nblk6][kt34][nt6][l][j]; kk<544 cos, kk>=544 -sin.
        const int tid = (bid - 4384) * 256 + threadIdx.x;        // 78,336
        const int l  = tid & 63;
        const int f  = tid >> 6;
        const int nt = f % 6;
        const int g  = f / 6;
        const int kt = g % 34;
        const int nblk = g / 34;
        const int n  = nblk * 96 + nt * 16 + (l & 15);
        const int kk0 = kt * 32 + (l >> 4) * 8;
        const float win = hannf(n) * (1.0f / 1024.0f);
        half8 o;
#pragma unroll
        for (int j = 0; j < 8; ++j) {
            const int kk = kk0 + j;
            float v = 0.0f;
            if (kk < 544) {
                const int k = kk;
                if (k < 513) {
                    const float coef = (k == 0 || k == 512) ? 1.0f : 2.0f;
                    v = coef * __cosf(TWO_PI_OVER_1024 * (float)((k * n) & 1023)) * win;
                }
            } else {
                const int k = kk - 544;
                if (k < 513) {
                    const float coef = (k == 0 || k == 512) ? 1.0f : 2.0f;
                    v = -coef * __sinf(TWO_PI_OVER_1024 * (float)((k * n) & 1023)) * win;
                }
            }
            o[j] = (_Float16)v;
        }
        *(half8*)(B2 + (size_t)tid * 8) = o;
    }
}

// ---------------- GEMM1: h = xh@Wh + b, fused activation -------------------
// Block 128m x 8 n-tiles (4 mag + 4 phase). Wave grid 2x2: wave w owns
// m-tiles wm..wm+3, n-tiles {2q,2q+1, 4+2q,5+2q} (matching mag+phase cols).
// 8 steps x 2 kt; per step per wave: 8 stage16, 16 ds_read_b128, 32 MFMA.

__device__ __forceinline__ void store_a2(_Float16* __restrict__ A2, int m, int k, float v)
{
    const int mt2 = m >> 4, mr = m & 15;
    const int kt2 = k >> 5, kc = k & 31;
    const int l2 = (kc >> 3) * 16 + mr;
    const int j2 = kc & 7;
    const int mtb = mt2 >> 3, mts = mt2 & 7;
    const size_t idx = ((((size_t)mtb * 34 + kt2) * 8 + mts) * 64 + l2) * 8 + j2;
    A2[idx] = (_Float16)v;
}

__global__ __launch_bounds__(256, 4)
void gemm1_k(const _Float16* __restrict__ A, const _Float16* __restrict__ B,
             const float* __restrict__ bias, _Float16* __restrict__ A2)
{
    __shared__ _Float16 Ash[2][8 * 512];   // 2 kt x 8 m-tiles (16 KB)
    __shared__ _Float16 Bsh[2][8 * 512];   // 2 kt x 8 n-tiles (16 KB)
    const int t = threadIdx.x, w = t >> 6, l = t & 63;

    // XCD-aware swizzle: 1152 blocks, 144 per XCD = 16 mblk x 9 bx.
    const int lin = blockIdx.x;
    const int xcd = lin & 7, slot = lin >> 3;
    const int mblk = xcd * 16 + slot / 9;
    const int bx   = slot % 9;

    const int wm = (w & 1) * 4;            // m-tile base
    const int q  = w >> 1;                 // n-pair index
    const int jt[4] = {2 * q, 2 * q + 1, 4 + 2 * q, 5 + 2 * q};

    f32x4 acc[4][4];                       // [m-tile][0..1 mag | 2..3 phase]
#pragma unroll
    for (int i = 0; i < 4; ++i)
#pragma unroll
        for (int j = 0; j < 4; ++j) acc[i][j] = (f32x4)0.0f;

    const int lane8 = l * 8;
    const _Float16* Ab = A + ((size_t)mblk * 16 * 8) * 512 + lane8;
    const _Float16* Bb = B + ((size_t)bx * 16 * 8) * 512 + lane8;

    for (int step = 0; step < 8; ++step) {
        const int kt0 = 2 * step;
        __syncthreads();
#pragma unroll
        for (int i = 0; i < 4; ++i) {
            const int s = 4 * w + i;
            const int u = s >> 3, r = s & 7;
            stage16(Ab + ((size_t)(kt0 + u) * 8 + r) * 512, &Ash[u][r * 512]);
            stage16(Bb + ((size_t)(kt0 + u) * 8 + r) * 512, &Bsh[u][r * 512]);
        }
        __syncthreads();

#pragma unroll
        for (int u = 0; u < 2; ++u) {
            half8 a[4], b[4];
#pragma unroll
            for (int i = 0; i < 4; ++i)
                a[i] = *(const half8*)&Ash[u][(wm + i) * 512 + lane8];
#pragma unroll
            for (int j = 0; j < 4; ++j)
                b[j] = *(const half8*)&Bsh[u][jt[j] * 512 + lane8];
#pragma unroll
            for (int i = 0; i < 4; ++i)
#pragma unroll
                for (int j = 0; j < 4; ++j)
                    acc[i][j] = __builtin_amdgcn_mfma_f32_16x16x32_f16(a[i], b[j], acc[i][j], 0, 0, 0);
        }
    }

    // epilogue: activation (HW transcendentals) + swizzled fp16 stores
    const int r4 = (l >> 4) * 4, c16 = l & 15;
#pragma unroll
    for (int i = 0; i < 4; ++i) {
        const int mbase = mblk * 128 + (wm + i) * 16 + r4;
#pragma unroll
        for (int p = 0; p < 2; ++p) {
            const int c = bx * 64 + (2 * q + p) * 16 + c16;   // [0,576)
            const bool valid = (c < 513);
            const float bm = valid ? bias[c] : 0.0f;
            const float bp = valid ? bias[513 + c] : 0.0f;
#pragma unroll
            for (int r = 0; r < 4; ++r) {
                float Sr = 0.0f, Si = 0.0f;
                if (valid) {
                    const float mag = fminf(__expf(acc[i][p][r] + bm), 100.0f);
                    const float ph  = acc[i][2 + p][r] + bp;
                    Sr = mag * __cosf(ph);
                    Si = mag * __sinf(ph);
                }
                if (c < 544) {
                    store_a2(A2, mbase + r, c, Sr);
                    store_a2(A2, mbase + r, 544 + c, Si);
                }
            }
        }
    }
}

// ---------------- GEMM2: mirror-symmetric frames = A2 @ basis ---------------
// Byte-identical to round 10 (= round 6 structure, best measured).

__device__ __forceinline__ void mma43(const _Float16* __restrict__ As,
                                      const _Float16* __restrict__ Bs,
                                      int wm, int wn, int lane16, f32x4 (&acc)[4][3])
{
    half8 a[4], b[3];
#pragma unroll
    for (int i = 0; i < 4; ++i) a[i] = *(const half8*)&As[(wm + i) * 512 + lane16];
#pragma unroll
    for (int j = 0; j < 3; ++j) b[j] = *(const half8*)&Bs[(wn + j) * 512 + lane16];
#pragma unroll
    for (int i = 0; i < 4; ++i)
#pragma unroll
        for (int j = 0; j < 3; ++j)
            acc[i][j] = __builtin_amdgcn_mfma_f32_16x16x32_f16(a[i], b[j], acc[i][j], 0, 0, 0);
}

__global__ __launch_bounds__(256, 3)
void gemm2_k(const _Float16* __restrict__ A, const _Float16* __restrict__ Bas,
             _Float16* __restrict__ C)
{
    __shared__ _Float16 As[2][8 * 512];   // 2 k-tiles x 128 m-rows
    __shared__ _Float16 Bs[2][6 * 512];   // 2 k-tiles x 96 n-cols
    const int t = threadIdx.x, w = t >> 6, l = t & 63;

    // XCD-aware swizzle: 768 blocks, 96 per XCD = 16 mblk x 6 nblk.
    const int lin = blockIdx.x;
    const int xcd = lin & 7, slot = lin >> 3;
    const int mblk = xcd * 16 + slot / 6;   // [0,128)
    const int nblk = slot % 6;              // [0,6)

    const int wm = (w & 1) * 4, wn = (w >> 1) * 3;

    f32x4 accC[4][3], accD[4][3];
#pragma unroll
    for (int i = 0; i < 4; ++i)
#pragma unroll
        for (int j = 0; j < 3; ++j) { accC[i][j] = (f32x4)0.0f; accD[i][j] = (f32x4)0.0f; }

    const int lane16 = l * 8;

    for (int step = 0; step < 17; ++step) {
        const int kt0 = 2 * step;
        __syncthreads();
#pragma unroll
        for (int i = 0; i < 4; ++i) {
            const int ta = 4 * w + i;
            const int u = ta >> 3, mts = ta & 7;
            const _Float16* Ag = A + ((((size_t)mblk * 34 + (kt0 + u)) * 8 + mts) * 512) + lane16;
            stage16(Ag, &As[u][mts * 512]);
        }
#pragma unroll
        for (int i = 0; i < 3; ++i) {
            const int tb = 3 * w + i;
            const int u = tb / 6, nt = tb % 6;
            const _Float16* Bg = Bas + ((((size_t)nblk * 34 + (kt0 + u)) * 6 + nt) * 512) + lane16;
            stage16(Bg, &Bs[u][nt * 512]);
        }
        __syncthreads();

#pragma unroll
        for (int u = 0; u < 2; ++u) {
            const int kt = kt0 + u;
            if (kt < 17) mma43(As[u], Bs[u], wm, wn, lane16, accC);
            else         mma43(As[u], Bs[u], wm, wn, lane16, accD);
        }
    }

    // epilogue: frames[n] = C+D, frames[1024-n] = C-D  (hann(1024-n)=hann(n))
    const int r4 = (l >> 4) * 4, c0 = l & 15;
#pragma unroll
    for (int i = 0; i < 4; ++i) {
        const int m = mblk * 128 + (wm + i) * 16 + r4;
#pragma unroll
        for (int j = 0; j < 3; ++j) {
            const int n = nblk * 96 + (wn + j) * 16 + c0;
#pragma unroll
            for (int r = 0; r < 4; ++r) {
                const float cv = accC[i][j][r];
                const float dv = accD[i][j][r];
                _Float16* row = C + (size_t)(m + r) * 1024;
                if (n < 513)           row[n]        = (_Float16)(cv + dv);
                if (n >= 1 && n < 512) row[1024 - n] = (_Float16)(cv - dv);
            }
        }
    }
}

// ---------------- overlap-add + envelope ------------------------------------

__global__ __launch_bounds__(256)
void ola_kernel(const _Float16* __restrict__ frames, float* __restrict__ out)
{
    const int idx = blockIdx.x * 256 + threadIdx.x;   // over 8 * 524288
    const int b = idx >> 19;
    const int j = idx & 524287;
    const int n = j + 384;

    int t_hi = n >> 8;
    if (t_hi > 2047) t_hi = 2047;
    const int t_lo = (n >= 1023) ? ((n - 1023 + 255) >> 8) : 0;

    float acc = 0.0f, env = 0.0f;
    for (int tt = t_lo; tt <= t_hi; ++tt) {
        const int s = n - (tt << 8);
        const float wv = hannf(s);
        acc += (float)frames[(((size_t)(b * 2048 + tt)) << 10) + s];
        env += wv * wv;
    }
    out[idx] = acc / env;
}

// ---------------- launch ----------------------------------------------------

extern "C" void kernel_launch(void* const* d_in, const int* in_sizes, int n_in,
                              void* d_out, int out_size, void* d_ws, size_t ws_size,
                              hipStream_t stream)
{
    const float* x = (const float*)d_in[0];   // 16384 x 512
    const float* W = (const float*)d_in[1];   // 512 x 1026
    const float* b = (const float*)d_in[2];   // 1026
    float* out = (float*)d_out;               // 8 x 524288
    char* ws = (char*)d_ws;

    _Float16* A2 = (_Float16*)(ws + OFF_A2);
    _Float16* B2 = (_Float16*)(ws + OFF_B2);
    _Float16* A1 = (_Float16*)(ws + OFF_A1);
    _Float16* B1 = (_Float16*)(ws + OFF_B1);
    _Float16* frames = (_Float16*)(ws + OFF_FR);

    prep_k<<<4690, 256, 0, stream>>>(x, W, A1, B1, B2);

    gemm1_k<<<1152, 256, 0, stream>>>(A1, B1, b, A2);
    gemm2_k<<<768, 256, 0, stream>>>(A2, B2, frames);

    ola_kernel<<<out_size / 256, 256, 0, stream>>>(frames, out);
}